// Round 1
// baseline (105.693 us; speedup 1.0000x reference)
//
#include <hip/hip_runtime.h>
#include <cmath>

// Sampler: temperature(0.7) -> top-p(0.9, HF ascending-cumsum semantics)
// -> top-k(50) -> softmax -> inverse-CDF multinomial with given uniform u.
//
// Reduction: final kept set = top min(m,50) tokens in descending value order,
// where m = nucleus size (descending cumulative prob crosses 0.9, inclusive).
// Sampled token = first kept token in ORIGINAL index order whose renormalized
// cumulative prob >= u (default token 0 if no crossing).

constexpr int   BLOCK  = 1024;
constexpr int   NBINS  = 4096;
constexpr int   CAP    = 1024;
constexpr int   TOPK   = 50;
constexpr float TEMP   = 0.7f;
constexpr float SPAN_L = 8.4f;   // histogram span below row max, logit units

__global__ __launch_bounds__(BLOCK)
void sampler_kernel(const float* __restrict__ logits,
                    const float* __restrict__ uvec,
                    int* __restrict__ out, int V)
{
  const int row  = blockIdx.x;
  const int tid  = threadIdx.x;
  const int lane = tid & 63;
  const int wave = tid >> 6;
  const float* __restrict__ lrow = logits + (size_t)row * (size_t)V;

  __shared__ unsigned int hist[NBINS];
  __shared__ float redf[BLOCK / 64];
  __shared__ float s_Ml;
  __shared__ float s_Z;
  __shared__ int   s_bstar;
  __shared__ unsigned int s_cnt;
  __shared__ float cand_l[CAP];
  __shared__ int   cand_i[CAP];
  __shared__ float kept_e[TOPK];
  __shared__ int   kept_i[TOPK];

  for (int i = tid; i < NBINS; i += BLOCK) hist[i] = 0u;
  if (tid == 0) s_cnt = 0u;

  // ---------- pass 1: row max (logit space) ----------
  const int V4 = ((V & 3) == 0) ? (V >> 2) : 0;
  const float4* l4 = reinterpret_cast<const float4*>(lrow);
  float m = -INFINITY;
  for (int i = tid; i < V4; i += BLOCK) {
    float4 v = l4[i];
    m = fmaxf(fmaxf(m, fmaxf(v.x, v.y)), fmaxf(v.z, v.w));
  }
  for (int i = (V4 << 2) + tid; i < V; i += BLOCK) m = fmaxf(m, lrow[i]);
  #pragma unroll
  for (int off = 32; off >= 1; off >>= 1) m = fmaxf(m, __shfl_xor(m, off, 64));
  if (lane == 0) redf[wave] = m;
  __syncthreads();
  if (tid < BLOCK / 64) {
    float v = redf[tid];
    #pragma unroll
    for (int off = 8; off >= 1; off >>= 1) v = fmaxf(v, __shfl_xor(v, off, 64));
    if (tid == 0) s_Ml = v;
  }
  __syncthreads();

  const float Ml = s_Ml;
  const float lo = Ml - SPAN_L;
  const float binscale = (float)NBINS / SPAN_L;
  const float invT = 1.0f / TEMP;

  // ---------- pass 2: softmax denominator Z + histogram of top region ----------
  float zs = 0.f;
  for (int i = tid; i < V4; i += BLOCK) {
    float4 v = l4[i];
    #pragma unroll
    for (int c = 0; c < 4; ++c) {
      float l = (c == 0) ? v.x : (c == 1) ? v.y : (c == 2) ? v.z : v.w;
      zs += expf((l - Ml) * invT);
      if (l > lo) {
        int b = (int)((l - lo) * binscale);
        if (b > NBINS - 1) b = NBINS - 1;
        atomicAdd(&hist[b], 1u);
      }
    }
  }
  for (int i = (V4 << 2) + tid; i < V; i += BLOCK) {
    float l = lrow[i];
    zs += expf((l - Ml) * invT);
    if (l > lo) {
      int b = (int)((l - lo) * binscale);
      if (b > NBINS - 1) b = NBINS - 1;
      atomicAdd(&hist[b], 1u);
    }
  }
  #pragma unroll
  for (int off = 32; off >= 1; off >>= 1) zs += __shfl_xor(zs, off, 64);
  if (lane == 0) redf[wave] = zs;
  __syncthreads();

  // ---------- threshold bin from histogram (wave 0) ----------
  if (tid < 64) {
    if (tid < BLOCK / 64) {
      float v = redf[tid];
      #pragma unroll
      for (int off = 8; off >= 1; off >>= 1) v += __shfl_xor(v, off, 64);
      if (tid == 0) s_Z = v;
    }
    unsigned int csum = 0;
    const int base = tid << 6;
    for (int j = 0; j < 64; ++j) csum += hist[base + j];
    unsigned int suf = 0;
    for (int l2 = 0; l2 < 64; ++l2) {
      unsigned int c2 = __shfl(csum, l2, 64);
      suf += (l2 >= tid) ? c2 : 0u;
    }
    unsigned long long bal = __ballot(suf >= (unsigned)TOPK);
    if (bal == 0ull) {
      if (tid == 0) s_bstar = 0;
    } else {
      int L = 63 - __builtin_clzll(bal);
      if (tid == L) {
        unsigned int running = suf - csum;   // suffix count above this chunk
        int bsel = base;
        for (int b = base + 63; b >= base; --b) {
          running += hist[b];
          if (running >= (unsigned)TOPK) { bsel = b; break; }
        }
        s_bstar = bsel;                      // largest bin with suffix >= TOPK
      }
    }
  }
  __syncthreads();

  // ---------- pass 3: collect candidates (bin >= bstar) ----------
  const int bstar = s_bstar;
  for (int i = tid; i < V4; i += BLOCK) {
    float4 v = l4[i];
    #pragma unroll
    for (int c = 0; c < 4; ++c) {
      float l = (c == 0) ? v.x : (c == 1) ? v.y : (c == 2) ? v.z : v.w;
      if (l > lo) {
        int b = (int)((l - lo) * binscale);
        if (b > NBINS - 1) b = NBINS - 1;
        if (b >= bstar) {
          unsigned int p = atomicAdd(&s_cnt, 1u);
          if (p < CAP) { cand_l[p] = l; cand_i[p] = (i << 2) + c; }
        }
      }
    }
  }
  for (int i = (V4 << 2) + tid; i < V; i += BLOCK) {
    float l = lrow[i];
    if (l > lo) {
      int b = (int)((l - lo) * binscale);
      if (b > NBINS - 1) b = NBINS - 1;
      if (b >= bstar) {
        unsigned int p = atomicAdd(&s_cnt, 1u);
        if (p < CAP) { cand_l[p] = l; cand_i[p] = i; }
      }
    }
  }
  __syncthreads();

  // ---------- phase 4: selection + nucleus cut + CDF sample (wave 0 only) ----------
  if (tid >= 64) return;

  const int n = ((int)s_cnt < CAP) ? (int)s_cnt : CAP;
  const float Mx = Ml / TEMP;            // exact reference path: fl(Ml/0.7)
  const float thresh = 0.9f * s_Z;
  float cum = 0.f;
  int nk = 0;

  for (int k = 0; k < TOPK; ++k) {
    if (cum >= thresh) break;            // nucleus: keep while cum_before < 0.9*Z
    float bv = -INFINITY; int bp = -1;
    for (int j = lane; j < n; j += 64) {
      float v = cand_l[j];
      if (v > bv) { bv = v; bp = j; }
    }
    #pragma unroll
    for (int off = 32; off >= 1; off >>= 1) {
      float ov = __shfl_xor(bv, off, 64);
      int   op = __shfl_xor(bp, off, 64);
      if (op >= 0 && (bp < 0 || ov > bv || (ov == bv && op < bp))) { bv = ov; bp = op; }
    }
    if (bp < 0) break;
    float x = cand_l[bp] / TEMP;         // exact reference path per element
    float e = expf(x - Mx);
    if (lane == 0) { kept_e[nk] = e; kept_i[nk] = cand_i[bp]; }
    nk++;
    cum += e;
    cand_l[bp] = -INFINITY;              // remove (uniform value, all lanes)
  }

  // rank-sort kept tokens by original index (all distinct)
  int   myi = 0x7fffffff;
  float mye = 0.f;
  if (lane < nk) { myi = kept_i[lane]; mye = kept_e[lane]; }
  int rank = 0;
  for (int j = 0; j < nk; ++j) rank += (kept_i[j] < myi) ? 1 : 0;
  if (lane < nk) { cand_l[rank] = mye; cand_i[rank] = myi; }

  if (lane == 0) {
    float S = 0.f;
    for (int j = 0; j < nk; ++j) S += cand_l[j];
    const float uu = uvec[row];
    float c = 0.f;
    int token = 0;                        // argmax over all-False -> 0
    for (int j = 0; j < nk; ++j) {
      float q = cand_l[j] / S;            // mirrors softmax's per-element divide
      c += q;
      if (c >= uu) { token = cand_i[j]; break; }
    }
    out[row] = token;
  }
}

extern "C" void kernel_launch(void* const* d_in, const int* in_sizes, int n_in,
                              void* d_out, int out_size, void* d_ws, size_t ws_size,
                              hipStream_t stream) {
  const float* logits = (const float*)d_in[0];
  // d_in[1] = input_ids (unused: repetition_penalty == 1.0)
  const float* u = (const float*)d_in[2];
  int* out = (int*)d_out;
  const int B = in_sizes[2];
  const int V = in_sizes[0] / B;
  hipLaunchKernelGGL(sampler_kernel, dim3(B), dim3(BLOCK), 0, stream,
                     logits, u, out, V);
}